// Round 9
// baseline (138.173 us; speedup 1.0000x reference)
//
#include <hip/hip_runtime.h>

// ConvTranspose3d (2,64,32^3) fp32 -> (2,32,66^3), stride2 pad1 outpad1 dil2 k3.
// Odd-grid MFMA: out[n,co,2dp+1,2hp+1,2wp+1] = bias[co] +
//   sum_{ci,kd,kh,kw} x[n,ci,dp+1-kd,hp+1-kh,wp+1-kw] * w[ci,co,kd,kh,kw]
// R9: R8's im2col-from-global + explicit per-tap-group register double-buffer
// (18 uint4 loads in flight while 12 MFMAs retire -> vmcnt(18) pipeline, no
// serialization). Boundary rows unified via zero-slab pointer select.

#define DOUT 66
#define PL (DOUT*DOUT)                   // 4356 floats/plane

typedef _Float16 half8 __attribute__((ext_vector_type(8)));
typedef float    floatx16 __attribute__((ext_vector_type(16)));

#define X16_N_STRIDE  2228224            // 32*32*34*64 f16
#define X16_ROW       2176               // 34*64 f16
#define ZSLAB_OFF     112640             // 8 KB zeros, byte offset in d_ws
#define X16_OFF       131072             // x16 byte offset in d_ws

// ---- k0: w (64,32,3,3,3) f32 -> wT[tap(27)][co(32)][ci(64)] f16 ----
__global__ void w_transpose(const float* __restrict__ w, _Float16* __restrict__ wT) {
    int o = blockIdx.x * 256 + threadIdx.x;          // o = tap*2048 + co*64 + ci
    if (o >= 27 * 32 * 64) return;
    int ci = o & 63, co = (o >> 6) & 31, tap = o >> 11;
    wT[o] = (_Float16)w[ci * (32 * 27) + co * 27 + tap];
}

// ---- k0b: x -> x16[n][id][ih][iwl 34][ci 64] f16 (iw halo zeroed) ----
__global__ void x_to_f16t(const float* __restrict__ x, _Float16* __restrict__ x16,
                          uint4* __restrict__ zslab) {
    const int tid = threadIdx.x;
    const unsigned b = blockIdx.x;                   // 256: id(5) | ihg(2) | n(1)
    const int id  = b & 31;
    const int ihg = (b >> 5) & 3;
    const int n   = b >> 7;
    const int iw  = tid & 31;
    const int ih  = ihg * 8 + (tid >> 5);

    if (b == 0) {                                    // 8 KB zero slab: 2 uint4/thr
        zslab[2 * tid]     = make_uint4(0, 0, 0, 0);
        zslab[2 * tid + 1] = make_uint4(0, 0, 0, 0);
    }

    const float* xr = x + (size_t)n * 2097152 + (id * 32 + ih) * 32 + iw;
    _Float16* drow = x16 + (size_t)n * X16_N_STRIDE + (id * 32 + ih) * X16_ROW;

    #pragma unroll
    for (int c0 = 0; c0 < 64; c0 += 16) {
        float f[16];
        #pragma unroll
        for (int j = 0; j < 16; ++j) f[j] = xr[(size_t)(c0 + j) * 32768];
        unsigned pk[8];
        #pragma unroll
        for (int j = 0; j < 8; ++j)
            pk[j] = __builtin_bit_cast(unsigned,
                        __builtin_amdgcn_cvt_pkrtz(f[2 * j], f[2 * j + 1]));
        _Float16* dst = drow + (iw + 1) * 64 + c0;
        ((uint4*)dst)[0] = make_uint4(pk[0], pk[1], pk[2], pk[3]);
        ((uint4*)dst)[1] = make_uint4(pk[4], pk[5], pk[6], pk[7]);
    }
    // zero halo: iwl = 0 and 33 for this block's 8 ih rows
    if (tid < 128) {
        const int side = tid >> 6;
        const int ihq2 = (tid >> 3) & 7;
        const int q    = tid & 7;
        _Float16* hz = x16 + (size_t)n * X16_N_STRIDE +
                       (id * 32 + ihg * 8 + ihq2) * X16_ROW + side * 33 * 64 + q * 8;
        ((uint4*)hz)[0] = make_uint4(0, 0, 0, 0);
    }
}

// ---- k1: bias over the 34 pure-bias planes per (n,co): od even + od=65 ----
#define BIAS_TOT4 (2*32*34*(PL/4))
__global__ void bias_planes(const float* __restrict__ bias, float* __restrict__ out) {
    const int tid = threadIdx.x;
    const unsigned base = blockIdx.x * 4096u;
    #pragma unroll
    for (int j = 0; j < 16; ++j) {
        unsigned idx = base + j * 256u + tid;
        if (idx >= BIAS_TOT4) continue;
        unsigned pl = idx / 1089u;
        unsigned slot = idx - pl * 1089u;
        unsigned e  = pl % 34u;
        unsigned nc = pl / 34u;
        unsigned od = (e < 33u) ? 2u * e : 65u;
        float v = bias[nc & 31u];
        float4* p = (float4*)(out + ((size_t)nc * DOUT + od) * PL);
        p[slot] = make_float4(v, v, v, v);
    }
}

// ---- per-(kd,kh) group fragment loader: 6 A + 12 B uint4 ----
__device__ __forceinline__ void load_group(
    int t9, const _Float16* wtl, const _Float16* xb, const _Float16* zr,
    int dp, int hp0, uint4* A, uint4* B)
{
    const int kd = t9 / 3, kh = t9 % 3;
    const int id  = dp + 1 - kd;
    const int ih0 = hp0 + 1 - kh;
    const bool iv = (unsigned)id < 32u;
    const bool v0 = iv && ((unsigned)ih0 < 32u);
    const bool v1 = iv && ((unsigned)(ih0 + 1) < 32u);
    const _Float16* base = xb + (id * 32 + ih0) * X16_ROW;
    const _Float16* bp0 = v0 ? base : zr;
    const _Float16* bp1 = v1 ? (base + X16_ROW) : zr;
    const _Float16* wt = wtl + t9 * 3 * 2048;
    #pragma unroll
    for (int kw = 0; kw < 3; ++kw) {
        const int off = (2 - kw) * 64;
        #pragma unroll
        for (int cc = 0; cc < 2; ++cc) {
            A[kw * 2 + cc]           = *(const uint4*)(wt + kw * 2048 + cc * 16);
            B[(kw * 2 + cc) * 2]     = *(const uint4*)(bp0 + off + cc * 16);
            B[(kw * 2 + cc) * 2 + 1] = *(const uint4*)(bp1 + off + cc * 16);
        }
    }
}

// ---- k2: MFMA conv, split-K wave pairs, register-double-buffered K-loop ----
__global__ void __launch_bounds__(256, 2) convt_mfma(
    const _Float16* __restrict__ x16, const _Float16* __restrict__ wT,
    const _Float16* __restrict__ zslab, const float* __restrict__ bias,
    float* __restrict__ out)
{
    __shared__ float redu[2][2][16][64];             // 16384 B

    const int tid  = threadIdx.x;
    const int lane = tid & 63;
    const int wv   = tid >> 6;
    const int pair = wv >> 1;
    const int kseg = wv & 1;

    unsigned b = blockIdx.x;                         // 512: xcd(3) | dp(5) | hq(1)
    const unsigned xcd = b & 7u;
    const int n   = xcd & 1;
    const int dp  = (b >> 3) & 31;
    const int hq  = b >> 8;
    const int hpg = (int)(((xcd >> 1) << 1) | hq);   // 0..7
    const int hp0 = hpg * 4 + pair * 2;

    const int wp  = lane & 31;
    const int kh8 = (lane >> 5) * 8;

    const _Float16* wtl = wT + (lane & 31) * 64 + kseg * 32 + kh8;
    const _Float16* xb  = x16 + (size_t)n * X16_N_STRIDE + wp * 64 + kseg * 32 + kh8;
    const _Float16* zr  = zslab + wp * 64 + kseg * 32 + kh8;

    floatx16 a0 = {}, a1 = {};
    uint4 Ab[2][6], Bb[2][12];

    load_group(0, wtl, xb, zr, dp, hp0, Ab[0], Bb[0]);
    #pragma unroll
    for (int g = 0; g < 9; ++g) {
        const int cur = g & 1, nxt = cur ^ 1;
        if (g < 8) load_group(g + 1, wtl, xb, zr, dp, hp0, Ab[nxt], Bb[nxt]);
        #pragma unroll
        for (int j = 0; j < 6; ++j) {
            a0 = __builtin_amdgcn_mfma_f32_32x32x16_f16(
                __builtin_bit_cast(half8, Ab[cur][j]),
                __builtin_bit_cast(half8, Bb[cur][2 * j]), a0, 0, 0, 0);
            a1 = __builtin_amdgcn_mfma_f32_32x32x16_f16(
                __builtin_bit_cast(half8, Ab[cur][j]),
                __builtin_bit_cast(half8, Bb[cur][2 * j + 1]), a1, 0, 0, 0);
        }
    }

    // ---- split-K reduction: kseg1 -> LDS, kseg0 adds ----
    if (kseg == 1) {
        #pragma unroll
        for (int r = 0; r < 16; ++r) {
            redu[pair][0][r][lane] = a0[r];
            redu[pair][1][r][lane] = a1[r];
        }
    }
    __syncthreads();

    const int od = 2 * dp + 1;
    if (kseg == 0) {
        #pragma unroll
        for (int r = 0; r < 16; ++r) {
            a0[r] += redu[pair][0][r][lane];
            a1[r] += redu[pair][1][r][lane];
        }
        #pragma unroll
        for (int t = 0; t < 2; ++t) {
            const int oh = 2 * (hp0 + t) + 1;
            const floatx16& acc = t ? a1 : a0;
            #pragma unroll
            for (int r = 0; r < 16; ++r) {
                const int co = (r & 3) + 8 * (r >> 2) + 4 * (lane >> 5);
                const float bv = bias[co];
                float2* orow = (float2*)(out +
                    ((size_t)(n * 32 + co) * DOUT + od) * PL + oh * DOUT);
                orow[wp] = make_float2(bv, acc[r] + bv);
                if (wp == 31) orow[32] = make_float2(bv, bv);
            }
        }
    } else {
        const bool tails = (hpg == 7) && (pair == 1);
        #pragma unroll
        for (int r = 0; r < 16; ++r) {
            const int co = (r & 3) + 8 * (r >> 2) + 4 * (lane >> 5);
            const float bv = bias[co];
            float* pbase = out + ((size_t)(n * 32 + co) * DOUT + od) * PL;
            #pragma unroll
            for (int t = 0; t < 2; ++t) {
                float2* erow = (float2*)(pbase + (2 * (hp0 + t)) * DOUT);
                erow[wp] = make_float2(bv, bv);
                if (wp == 31) erow[32] = make_float2(bv, bv);
            }
            if (tails) {
                float2* t0 = (float2*)(pbase + 64 * DOUT);
                float2* t1 = (float2*)(pbase + 65 * DOUT);
                t0[wp] = make_float2(bv, bv);
                t1[wp] = make_float2(bv, bv);
                if (wp == 31) { t0[32] = make_float2(bv, bv); t1[32] = make_float2(bv, bv); }
            }
        }
    }
}

extern "C" void kernel_launch(void* const* d_in, const int* in_sizes, int n_in,
                              void* d_out, int out_size, void* d_ws, size_t ws_size,
                              hipStream_t stream) {
    const float* x    = (const float*)d_in[0];
    const float* wgt  = (const float*)d_in[1];
    const float* bias = (const float*)d_in[2];
    float* out = (float*)d_out;
    _Float16* wT    = (_Float16*)d_ws;                       // [0, 110592)
    uint4*    zslab = (uint4*)((char*)d_ws + ZSLAB_OFF);     // 8 KB zeros
    _Float16* x16   = (_Float16*)((char*)d_ws + X16_OFF);    // 8.9 MB

    w_transpose<<<216, 256, 0, stream>>>(wgt, wT);
    x_to_f16t<<<256, 256, 0, stream>>>(x, x16, zslab);
    bias_planes<<<(BIAS_TOT4 + 4095) / 4096, 256, 0, stream>>>(bias, out);
    convt_mfma<<<512, 256, 0, stream>>>(x16, wT, (const _Float16*)zslab, bias, out);
}

// Round 10
// 110.782 us; speedup vs baseline: 1.2473x; 1.2473x over previous
//
#include <hip/hip_runtime.h>

// ConvTranspose3d (2,64,32^3) fp32 -> (2,32,66^3), stride2 pad1 outpad1 dil2 k3.
// Odd-grid MFMA: out[n,co,2dp+1,2hp+1,2wp+1] = bias[co] +
//   sum_{ci,kd,kh,kw} x[n,ci,dp+1-kd,hp+1-kh,wp+1-kw] * w[ci,co,kd,kh,kw]
// R10: decouple counters. B path: x16 (repacked) --global_load_lds DMA--> LDS
// --ds_read_b128 (conflict-free)--> MFMA. A path: 27 uint4 batch-loaded to
// registers before the barrier. K-loop = pure ds_read+MFMA (lgkmcnt only).
// Split-K across the 4 waves (one 16-ci chunk each), reduced through LDS.

#define DOUT 66
#define PL (DOUT*DOUT)                  // 4356 floats/plane

typedef _Float16 half8 __attribute__((ext_vector_type(8)));
typedef float    floatx16 __attribute__((ext_vector_type(16)));

#define X16_N_F16  2228224              // f16 per n: 32*32*2176
#define ROW_B      4352                 // bytes per (id,ih) row: 8ccg*34iwl*8ci*2
#define ZSLAB_OFF  112640               // 8 KB zeros
#define X16_OFF    131072

// ---- k0: w (64,32,3,3,3) f32 -> wA[cc 4][tap 27][lane 64][8 f16] ----
// lane = co + 32*khalf; element j -> ci = cc*16 + khalf*8 + j (A/B k-maps match).
__global__ void w_prep(const float* __restrict__ w, _Float16* __restrict__ wA) {
    int o = blockIdx.x * 256 + threadIdx.x;
    if (o >= 55296) return;
    int j = o & 7;
    int tmp = o >> 3;
    int lane = tmp & 63;
    int g = tmp >> 6;                    // cc*27 + tap
    int cc = g / 27, tap = g - cc * 27;
    int co = lane & 31, khalf = lane >> 5;
    int ci = cc * 16 + khalf * 8 + j;
    wA[o] = (_Float16)w[ci * 864 + co * 27 + tap];
}

// ---- k0b: x -> x16[n][id][ih][ccg 8][iwl 34][ci8 8] f16; halo zeroed ----
__global__ void x_to_f16t(const float* __restrict__ x, _Float16* __restrict__ x16,
                          uint4* __restrict__ zslab) {
    const int tid = threadIdx.x;
    const unsigned b = blockIdx.x;       // 256: id(5) | ihg(2) | n(1)
    const int id  = b & 31;
    const int ihg = (b >> 5) & 3;
    const int n   = b >> 7;
    const int iw  = tid & 31;
    const int ih  = ihg * 8 + (tid >> 5);

    if (b == 0) {                        // 8 KB zero slab
        zslab[2 * tid]     = make_uint4(0, 0, 0, 0);
        zslab[2 * tid + 1] = make_uint4(0, 0, 0, 0);
    }

    const float* xr = x + (size_t)n * 2097152 + (id * 32 + ih) * 32 + iw;
    _Float16* drow = x16 + (size_t)n * X16_N_F16 + (id * 32 + ih) * 2176;

    #pragma unroll
    for (int c0 = 0; c0 < 64; c0 += 16) {
        float f[16];
        #pragma unroll
        for (int j = 0; j < 16; ++j) f[j] = xr[(size_t)(c0 + j) * 32768];
        unsigned pk[8];
        #pragma unroll
        for (int j = 0; j < 8; ++j)
            pk[j] = __builtin_bit_cast(unsigned,
                        __builtin_amdgcn_cvt_pkrtz(f[2 * j], f[2 * j + 1]));
        const int ccg0 = c0 >> 3;
        *(uint4*)(drow + ccg0 * 272 + (iw + 1) * 8) =
            make_uint4(pk[0], pk[1], pk[2], pk[3]);
        *(uint4*)(drow + (ccg0 + 1) * 272 + (iw + 1) * 8) =
            make_uint4(pk[4], pk[5], pk[6], pk[7]);
    }
    // halo: 8 ih rows x 8 ccg x {iwl 0, 33}
    if (tid < 128) {
        const int ihq = tid >> 4;
        const int rem = tid & 15;
        const int ccg = rem >> 1, side = rem & 1;
        _Float16* hz = x16 + (size_t)n * X16_N_F16 +
                       (id * 32 + ihg * 8 + ihq) * 2176 + ccg * 272 + (side ? 264 : 0);
        *(uint4*)hz = make_uint4(0, 0, 0, 0);
    }
}

// ---- k1: bias over the 34 pure-bias planes per (n,co): od even + od=65 ----
#define BIAS_TOT4 (2*32*34*(PL/4))
__global__ void bias_planes(const float* __restrict__ bias, float* __restrict__ out) {
    const int tid = threadIdx.x;
    const unsigned base = blockIdx.x * 4096u;
    #pragma unroll
    for (int j = 0; j < 16; ++j) {
        unsigned idx = base + j * 256u + tid;
        if (idx >= BIAS_TOT4) continue;
        unsigned pl = idx / 1089u;
        unsigned slot = idx - pl * 1089u;
        unsigned e  = pl % 34u;
        unsigned nc = pl / 34u;
        unsigned od = (e < 33u) ? 2u * e : 65u;
        float v = bias[nc & 31u];
        float4* p = (float4*)(out + ((size_t)nc * DOUT + od) * PL);
        p[slot] = make_float4(v, v, v, v);
    }
}

// ---- k2: DMA-staged MFMA conv ----
__global__ void __launch_bounds__(256, 2) convt_mfma(
    const _Float16* __restrict__ x16, const _Float16* __restrict__ wA,
    const _Float16* __restrict__ zslab, const float* __restrict__ bias,
    float* __restrict__ out)
{
    __shared__ __align__(16) unsigned char xlds[78848];   // 18 rows x 4352 B (+pad)

    const int tid  = threadIdx.x;
    const int lane = tid & 63;
    const int wv   = tid >> 6;           // wave = cc chunk

    unsigned b = blockIdx.x;             // 512: xcd(3) | dp(5) | hq(1)
    const unsigned xcd = b & 7u;
    const int n   = xcd & 1;
    const int dp  = (b >> 3) & 31;
    const int hq  = b >> 8;
    const int hpg = (int)(((xcd >> 1) << 1) | hq);        // 0..7
    const int hpb = hpg * 4;

    // ---- A: 27 uint4 batch load (single vmcnt drain at the barrier) ----
    uint4 A[27];
    const _Float16* wl = wA + ((size_t)wv * 27 * 64 + lane) * 8;
    #pragma unroll
    for (int t = 0; t < 27; ++t) A[t] = *(const uint4*)(wl + t * 512);

    // ---- B: async DMA rows (id,ih) -> LDS linear; invalid rows from zslab ----
    const char* xby = (const char*)(x16 + (size_t)n * X16_N_F16);
    const char* zby = (const char*)zslab;
    for (int m = wv; m < 77; m += 4) {   // 77 wave-instrs x 1024 B
        int c = m * 64 + lane;           // 16B chunk index
        int r = c / 272;                 // source row 0..18
        int q = c - r * 272;
        const char* g;
        if (r < 18) {
            int idl = r / 6, ihl = r - idl * 6;
            int id = dp - 1 + idl, ih = hpb - 1 + ihl;
            bool v = ((unsigned)id < 32u) & ((unsigned)ih < 32u);
            g = v ? (xby + (id * 32 + ih) * ROW_B + q * 16) : (zby + q * 16);
        } else {
            g = zby;
        }
        __builtin_amdgcn_global_load_lds(
            (const __attribute__((address_space(1))) void*)g,
            (__attribute__((address_space(3))) void*)(xlds + m * 1024),
            16, 0, 0);
    }
    __syncthreads();

    // ---- K-loop: pure ds_read_b128 + MFMA, 4 independent acc chains ----
    const int wp    = lane & 31;
    const int khalf = lane >> 5;
    const int cbase = (2 * wv + khalf) * 544 + wp * 16;   // byte base in row

    floatx16 acc[4] = {{}, {}, {}, {}};
    #pragma unroll
    for (int kd = 0; kd < 3; ++kd)
    #pragma unroll
    for (int kh = 0; kh < 3; ++kh)
    #pragma unroll
    for (int kw = 0; kw < 3; ++kw) {
        const int tap = (kd * 3 + kh) * 3 + kw;
        #pragma unroll
        for (int t = 0; t < 4; ++t) {
            const int row = (2 - kd) * 6 + (t + 2 - kh);
            const uint4* bp = (const uint4*)(xlds + row * ROW_B + cbase + (2 - kw) * 16);
            acc[t] = __builtin_amdgcn_mfma_f32_32x32x16_f16(
                __builtin_bit_cast(half8, A[tap]),
                __builtin_bit_cast(half8, *bp), acc[t], 0, 0, 0);
        }
    }

    // ---- split-K reduction through the (now free) LDS ----
    __syncthreads();
    float* part = (float*)xlds;
    if (wv > 0) {
        #pragma unroll
        for (int t = 0; t < 4; ++t)
            #pragma unroll
            for (int r = 0; r < 16; ++r)
                part[((wv - 1) * 64 + t * 16 + r) * 64 + lane] = acc[t][r];
    }
    __syncthreads();

    const int od = 2 * dp + 1;
    if (wv == 0) {
        #pragma unroll
        for (int t = 0; t < 4; ++t) {
            const int oh = 2 * (hpb + t) + 1;
            #pragma unroll
            for (int r = 0; r < 16; ++r) {
                float s = acc[t][r]
                    + part[(t * 16 + r) * 64 + lane]
                    + part[(64 + t * 16 + r) * 64 + lane]
                    + part[(128 + t * 16 + r) * 64 + lane];
                const int co = (r & 3) + 8 * (r >> 2) + 4 * khalf;  // verified C/D map
                const float bv = bias[co];
                float2* orow = (float2*)(out +
                    ((size_t)(n * 32 + co) * DOUT + od) * PL + oh * DOUT);
                orow[wp] = make_float2(bv, s + bv);
                if (wp == 31) orow[32] = make_float2(bv, bv);
            }
        }
    } else if (wv <= 2) {
        #pragma unroll
        for (int tt = 0; tt < 2; ++tt) {
            const int oh = 2 * (hpb + (wv - 1) * 2 + tt);
            #pragma unroll
            for (int r = 0; r < 16; ++r) {
                const int co = (r & 3) + 8 * (r >> 2) + 4 * khalf;
                const float bv = bias[co];
                float2* erow = (float2*)(out +
                    ((size_t)(n * 32 + co) * DOUT + od) * PL + oh * DOUT);
                erow[wp] = make_float2(bv, bv);
                if (wp == 31) erow[32] = make_float2(bv, bv);
            }
        }
    } else if (hpg == 7) {
        #pragma unroll
        for (int tt = 0; tt < 2; ++tt) {
            const int oh = 64 + tt;
            #pragma unroll
            for (int r = 0; r < 16; ++r) {
                const int co = (r & 3) + 8 * (r >> 2) + 4 * khalf;
                const float bv = bias[co];
                float2* erow = (float2*)(out +
                    ((size_t)(n * 32 + co) * DOUT + od) * PL + oh * DOUT);
                erow[wp] = make_float2(bv, bv);
                if (wp == 31) erow[32] = make_float2(bv, bv);
            }
        }
    }
}

extern "C" void kernel_launch(void* const* d_in, const int* in_sizes, int n_in,
                              void* d_out, int out_size, void* d_ws, size_t ws_size,
                              hipStream_t stream) {
    const float* x    = (const float*)d_in[0];
    const float* wgt  = (const float*)d_in[1];
    const float* bias = (const float*)d_in[2];
    float* out = (float*)d_out;
    _Float16* wA    = (_Float16*)d_ws;                    // [0, 110592)
    uint4*    zslab = (uint4*)((char*)d_ws + ZSLAB_OFF);  // 8 KB zeros
    _Float16* x16   = (_Float16*)((char*)d_ws + X16_OFF); // 8.9 MB

    w_prep<<<216, 256, 0, stream>>>(wgt, wA);
    x_to_f16t<<<256, 256, 0, stream>>>(x, x16, zslab);
    bias_planes<<<(BIAS_TOT4 + 4095) / 4096, 256, 0, stream>>>(bias, out);
    convt_mfma<<<512, 256, 0, stream>>>(x16, wA, (const _Float16*)zslab, bias, out);
}